// Round 13
// baseline (1135.354 us; speedup 1.0000x reference)
//
#include <hip/hip_runtime.h>
#include <stdint.h>

#define N_PTS 8192
#define N_B 8
#define NGROUP 512
#define GSIZE 32
#define BIGF 1e10f

#define THREADS 512
#define TOT_BLOCKS 256
#define FPS_BLOCKS 8
#define KNN_BLOCKS (TOT_BLOCKS - FPS_BLOCKS)   // 248

#define K1_CTH 256           // fps compute threads
#define K1_PPT 32
#define K1_WAVES 4

#define K2_PPT 16
#define K2_WAVES 8

// ---------------- DPP reductions ------------------------------------------------------
#define DPP_STEP_UMIN(ctrl, rmask)                                                 \
    { unsigned t = (unsigned)__builtin_amdgcn_update_dpp(                          \
            (int)v, (int)v, ctrl, rmask, 0xF, false);                              \
      v = (t < v) ? t : v; }

__device__ __forceinline__ unsigned wave_umin32(unsigned v) {
    DPP_STEP_UMIN(0x111, 0xF);
    DPP_STEP_UMIN(0x112, 0xF);
    DPP_STEP_UMIN(0x114, 0xF);
    DPP_STEP_UMIN(0x118, 0xF);
    DPP_STEP_UMIN(0x142, 0xA);
    DPP_STEP_UMIN(0x143, 0xC);
    return v;   // lane 63 valid
}

#define DPP_STEP_FMAX(ctrl, rmask)                                                 \
    v = fmaxf(v, __int_as_float(__builtin_amdgcn_update_dpp(                       \
            __float_as_int(v), __float_as_int(v), ctrl, rmask, 0xF, false)))

__device__ __forceinline__ float wave_fmax(float v) {
    DPP_STEP_FMAX(0x111, 0xF);
    DPP_STEP_FMAX(0x112, 0xF);
    DPP_STEP_FMAX(0x114, 0xF);
    DPP_STEP_FMAX(0x118, 0xF);
    DPP_STEP_FMAX(0x142, 0xA);
    DPP_STEP_FMAX(0x143, 0xC);
    return v;   // lane 63 valid
}

#define U64_DPP_STEP(ctrl, rmask, CMPOP)                                           \
    { unsigned lo_ = (unsigned)v, hi_ = (unsigned)(v >> 32);                       \
      unsigned olo = (unsigned)__builtin_amdgcn_update_dpp((int)lo_, (int)lo_, ctrl, rmask, 0xF, false); \
      unsigned ohi = (unsigned)__builtin_amdgcn_update_dpp((int)hi_, (int)hi_, ctrl, rmask, 0xF, false); \
      unsigned long long o = ((unsigned long long)ohi << 32) | olo;                \
      if (o CMPOP v) v = o; }

__device__ __forceinline__ int rdlane63_i(int v) {
    return __builtin_amdgcn_readlane(v, 63);
}

// Exact (no-FMA) squared distance in numpy's evaluation order: (dx^2 + dy^2) + dz^2
__device__ __forceinline__ float sq_dist(float x, float y, float z,
                                         float cx, float cy, float cz) {
    float dx = __fsub_rn(x, cx);
    float dy = __fsub_rn(y, cy);
    float dz = __fsub_rn(z, cz);
    return __fadd_rn(__fadd_rn(__fmul_rn(dx, dx), __fmul_rn(dy, dy)), __fmul_rn(dz, dz));
}

__device__ __forceinline__ unsigned fxform(unsigned u) {
    return u ^ (unsigned)(((int)u >> 31) | 0x80000000);
}

// bitonic sort (ascending) of an N-element register array of u64
template<int N>
__device__ __forceinline__ void bitonic_sort(unsigned long long* a) {
#pragma unroll
    for (int k = 2; k <= N; k <<= 1) {
#pragma unroll
        for (int j = k >> 1; j > 0; j >>= 1) {
#pragma unroll
            for (int i = 0; i < N; ++i) {
                int ixj = i ^ j;
                if (ixj > i) {
                    bool up = ((i & k) == 0);
                    unsigned long long x = a[i], y = a[ixj];
                    bool sw = up ? (x > y) : (x < y);
                    if (sw) { a[i] = y; a[ixj] = x; }
                }
            }
        }
    }
}

// LDS overlay: fps needs lx/ly/lz + part; knn needs wtop + nlist. 1 block/CU by LDS.
union SharedLDS {
    struct {
        float lx[N_PTS]; float ly[N_PTS]; float lz[N_PTS];   // 96 KB
        unsigned part[2][K1_WAVES][8];
    } f;
    struct {
        unsigned long long wtop[K2_WAVES][GSIZE];            // 2 KB
        unsigned nlist[GSIZE];
    } k;
};

// ---------------- fused kernel --------------------------------------------------------
// Blocks 0..7: FPS for batch b (R10 body, tid<256 active). After writing group it,
// release-store progress[b]=it+1 (device scope).
// Blocks 8..255: kNN workers; consume groups in ready-order idx=g*8+b, stride 248;
// acquire-spin on progress[b] > g, then R10 knn body.
extern "C" __global__ __launch_bounds__(THREADS, 1) void fused_kernel(
    const float* __restrict__ xyz, float* __restrict__ out,
    int* __restrict__ fps_idx, int* __restrict__ progress)
{
    __shared__ SharedLDS S;
    const int bid = blockIdx.x;
    const int tid = threadIdx.x;
    const int lane = tid & 63;
    const int wid  = tid >> 6;

    if (bid < FPS_BLOCKS) {
        // =========================== FPS (batch = bid) ===============================
        const int b = bid;
        const float* base = xyz + (size_t)b * N_PTS * 6;
        const float4* b4 = (const float4*)base;

        if (tid < K1_CTH) {
            float sx[K1_PPT], sy[K1_PPT], sz[K1_PPT], dd[K1_PPT];
            const int tb = tid * 48;
#pragma unroll
            for (int c = 0; c < 8; ++c) {
                float4 f0 = b4[tb + c * 6 + 0];
                float4 f1 = b4[tb + c * 6 + 1];
                float4 f2 = b4[tb + c * 6 + 2];
                float4 f3 = b4[tb + c * 6 + 3];
                float4 f4 = b4[tb + c * 6 + 4];
                float4 f5 = b4[tb + c * 6 + 5];
                sx[c*4+0] = f0.x; sy[c*4+0] = f0.y; sz[c*4+0] = f0.z;
                sx[c*4+1] = f1.z; sy[c*4+1] = f1.w; sz[c*4+1] = f2.x;
                sx[c*4+2] = f3.x; sy[c*4+2] = f3.y; sz[c*4+2] = f3.z;
                sx[c*4+3] = f4.z; sy[c*4+3] = f4.w; sz[c*4+3] = f5.x;
            }
            // swizzled staging: point p = tid*32+i at A(p) = (i<<8)+tid (conflict-free)
#pragma unroll
            for (int i = 0; i < K1_PPT; ++i) {
                int a = (i << 8) + tid;
                S.f.lx[a] = sx[i]; S.f.ly[a] = sy[i]; S.f.lz[a] = sz[i];
                dd[i] = BIGF;
            }
            __syncthreads();

            unsigned cur = 0;
            float cx = S.f.lx[0], cy = S.f.ly[0], cz = S.f.lz[0];

            for (int it = 0; it < NGROUP; ++it) {
                if (tid == 0) {
                    fps_idx[b * NGROUP + it] = (int)cur;
                    __hip_atomic_store(&progress[b], it + 1,
                                       __ATOMIC_RELEASE, __HIP_MEMORY_SCOPE_AGENT);
                }
                if (it == NGROUP - 1) break;

                // min-update + inline first-max tracking
                float bestd = -1.0f;
                unsigned besti = 0;
#pragma unroll
                for (int i = 0; i < K1_PPT; ++i) {
                    float d = sq_dist(sx[i], sy[i], sz[i], cx, cy, cz);
                    dd[i] = fminf(dd[i], d);
                    bool gt = dd[i] > bestd;
                    bestd = gt ? dd[i] : bestd;
                    besti = gt ? (unsigned)i : besti;
                }
                unsigned bestp = (unsigned)tid * K1_PPT + besti;

                // wave argmax: f32 DPP max, then first tied lane (= smallest index)
                float wm = __int_as_float(rdlane63_i(__float_as_int(wave_fmax(bestd))));
                unsigned long long bal = __ballot(bestd == wm);
                int L = (int)(__ffsll((long long)bal) - 1);
                unsigned widx = (unsigned)__builtin_amdgcn_readlane((int)bestp, L);

                if (lane == 0) {
                    int wa = (int)(((widx & 31u) << 8) + (widx >> 5));
                    unsigned* pp = S.f.part[it & 1][wid];
                    pp[0] = 0xFFFFFFFFu - widx;
                    pp[1] = __float_as_uint(wm);
                    pp[2] = __float_as_uint(S.f.lx[wa]);
                    pp[3] = __float_as_uint(S.f.ly[wa]);
                    pp[4] = __float_as_uint(S.f.lz[wa]);
                }
                __syncthreads();

                // block reduce over 4 partials (lanes 0..3), max valid in lane 3
                const unsigned* pp = S.f.part[it & 1][lane & 3];
                unsigned kl = pp[0], kh = pp[1];
                float xx = __uint_as_float(pp[2]);
                float yy = __uint_as_float(pp[3]);
                float zz = __uint_as_float(pp[4]);
                unsigned long long v = ((unsigned long long)kh << 32) | kl;
                U64_DPP_STEP(0x111, 0xF, >);
                U64_DPP_STEP(0x112, 0xF, >);
                unsigned wkl = (unsigned)__builtin_amdgcn_readlane((int)(unsigned)v, 3);
                cur = 0xFFFFFFFFu - wkl;
                int W = (int)(cur >> 11);   // 2048 pts/wave -> winning wave id
                cx = __int_as_float(__builtin_amdgcn_readlane(__float_as_int(xx), W));
                cy = __int_as_float(__builtin_amdgcn_readlane(__float_as_int(yy), W));
                cz = __int_as_float(__builtin_amdgcn_readlane(__float_as_int(zz), W));
            }
        } else {
            // idle waves: mirror the barrier count (1 staging + 511 iteration barriers)
            __syncthreads();
            for (int it = 0; it < NGROUP - 1; ++it) __syncthreads();
        }
        return;
    }

    // ============================= kNN worker blocks =================================
    const int OFF1 = N_B * NGROUP * GSIZE * 3;   // neigh_attr
    const int OFF2 = 2 * OFF1;                   // center
    const int OFF3 = OFF2 + N_B * NGROUP * 3;    // center_attribute

    for (int idx = bid - FPS_BLOCKS; idx < N_B * NGROUP; idx += KNN_BLOCKS) {
        const int g = idx >> 3;
        const int b = idx & 7;
        const float* base = xyz + (size_t)b * N_PTS * 6;

        if (tid == 0) {
            while (__hip_atomic_load(&progress[b], __ATOMIC_ACQUIRE,
                                     __HIP_MEMORY_SCOPE_AGENT) <= g)
                __builtin_amdgcn_s_sleep(2);
        }
        __syncthreads();

        const int q  = fps_idx[b * NGROUP + g];
        const int qq = __builtin_amdgcn_readfirstlane(q);
        const float cx = base[qq * 6 + 0];
        const float cy = base[qq * 6 + 1];
        const float cz = base[qq * 6 + 2];
        // ||c||^2: separate square, left-assoc add, NO FMA
        const float cn = __fadd_rn(__fadd_rn(__fmul_rn(cx, cx), __fmul_rn(cy, cy)),
                                   __fmul_rn(cz, cz));

        const float4* b4 = (const float4*)base;
        const int tb = tid * 24;

        unsigned long long keys[K2_PPT];

#pragma unroll
        for (int c = 0; c < 4; ++c) {
            float4 f0 = b4[tb + c * 6 + 0];
            float4 f1 = b4[tb + c * 6 + 1];
            float4 f2 = b4[tb + c * 6 + 2];
            float4 f3 = b4[tb + c * 6 + 3];
            float4 f4 = b4[tb + c * 6 + 4];
            float4 f5 = b4[tb + c * 6 + 5];
            float X[4] = {f0.x, f1.z, f3.x, f4.z};
            float Y[4] = {f0.y, f1.w, f3.y, f4.w};
            float Z[4] = {f0.z, f2.x, f3.z, f5.x};
#pragma unroll
            for (int j = 0; j < 4; ++j) {
                float x = X[j], y = Y[j], z = Z[j];
                float xn  = __fadd_rn(__fadd_rn(__fmul_rn(x, x), __fmul_rn(y, y)), __fmul_rn(z, z));
                float dot = __fmul_rn(cx, x);
                dot = __fmaf_rn(cy, y, dot);
                dot = __fmaf_rn(cz, z, dot);
                float d2  = __fadd_rn(__fsub_rn(cn, __fmul_rn(2.0f, dot)), xn);
                int p = tid * K2_PPT + c * 4 + j;
                keys[c * 4 + j] =
                    ((unsigned long long)fxform(__float_as_uint(d2)) << 32) | (unsigned)p;
            }
        }

        bitonic_sort<K2_PPT>(keys);

        // per-wave top-32 extraction (ascending into wtop[wid])
        {
            unsigned long long cand = keys[0];
            unsigned w = 0;
            for (int r = 0; r < GSIZE; ++r) {
                unsigned ch = (unsigned)(cand >> 32);
                unsigned whd = (unsigned)rdlane63_i((int)wave_umin32(ch));
                unsigned long long bal = __ballot(ch == whd);
                unsigned wl;
                if (__popcll(bal) == 1) {
                    int L = (int)(__ffsll((long long)bal) - 1);
                    wl = (unsigned)__builtin_amdgcn_readlane((int)(unsigned)cand, L);
                } else {
                    unsigned cl = (ch == whd) ? (unsigned)cand : 0xFFFFFFFFu;
                    wl = (unsigned)rdlane63_i((int)wave_umin32(cl));
                }
                unsigned long long wkey = ((unsigned long long)whd << 32) | wl;
                if (lane == 0) S.k.wtop[wid][r] = wkey;
                if (cand == wkey) {   // exactly one lane (keys unique)
                    ++w;
                    unsigned long long nc;
                    if (w < 4) {
                        nc = (w == 1) ? keys[1] : (w == 2) ? keys[2] : keys[3];
                    } else if (w < K2_PPT) {
                        nc = keys[4];
#pragma unroll
                        for (int j = 5; j < K2_PPT; ++j) nc = (w == (unsigned)j) ? keys[j] : nc;
                    } else {
                        nc = ~0ull;
                    }
                    cand = nc;
                }
            }
        }
        __syncthreads();

        // parallel rank-merge: 256 threads, one candidate each
        if (tid < K2_WAVES * GSIZE) {
            const int w8 = tid >> 5, i = tid & 31;
            unsigned long long e = S.k.wtop[w8][i];
            int rank = 0;
#pragma unroll
            for (int l = 0; l < K2_WAVES; ++l) {
                const unsigned long long* arr = S.k.wtop[l];
                int lo = 0;
                if (arr[15]     < e) lo = 16;
                if (arr[lo + 7] < e) lo += 8;
                if (arr[lo + 3] < e) lo += 4;
                if (arr[lo + 1] < e) lo += 2;
                if (arr[lo]     < e) lo += 1;
                rank += lo;
            }
            if (rank < GSIZE) S.k.nlist[rank] = (unsigned)e;
        }
        __syncthreads();

        // ---- outputs ----
        if (tid < GSIZE) {
            unsigned p = S.k.nlist[tid];
            float x  = base[p * 6 + 0];
            float y  = base[p * 6 + 1];
            float z  = base[p * 6 + 2];
            float a0 = base[p * 6 + 3];
            float a1 = base[p * 6 + 4];
            float a2 = base[p * 6 + 5];
            size_t o = ((size_t)(b * NGROUP + g) * GSIZE + tid) * 3;
            out[o + 0] = __fsub_rn(x, cx);
            out[o + 1] = __fsub_rn(y, cy);
            out[o + 2] = __fsub_rn(z, cz);
            out[OFF1 + o + 0] = a0;
            out[OFF1 + o + 1] = a1;
            out[OFF1 + o + 2] = a2;
        } else if (tid == GSIZE) {
            size_t o = (size_t)(b * NGROUP + g) * 3;
            out[OFF2 + o + 0] = cx;
            out[OFF2 + o + 1] = cy;
            out[OFF2 + o + 2] = cz;
            out[OFF3 + o + 0] = base[qq * 6 + 3];
            out[OFF3 + o + 1] = base[qq * 6 + 4];
            out[OFF3 + o + 2] = base[qq * 6 + 5];
        }
    }
}

extern "C" void kernel_launch(void* const* d_in, const int* in_sizes, int n_in,
                              void* d_out, int out_size, void* d_ws, size_t ws_size,
                              hipStream_t stream) {
    const float* xyz = (const float*)d_in[0];
    float* out = (float*)d_out;
    int* fps_idx  = (int*)d_ws;                          // 16 KB
    int* progress = (int*)((char*)d_ws + 16384);         // 8 ints; 0xAA poison < 0 => spin

    fused_kernel<<<TOT_BLOCKS, THREADS, 0, stream>>>(xyz, out, fps_idx, progress);
}

// Round 14
// 983.492 us; speedup vs baseline: 1.1544x; 1.1544x over previous
//
#include <hip/hip_runtime.h>
#include <stdint.h>

#define N_PTS 8192
#define N_B 8
#define NGROUP 512
#define GSIZE 32
#define BIGF 1e10f

#define THREADS 512
#define TOT_BLOCKS 256
#define FPS_BLOCKS 8
#define KNN_BLOCKS (TOT_BLOCKS - FPS_BLOCKS)   // 248

#define K1_PPT 16            // fps points per thread (fits 88-VGPR budget: R9 evidence)
#define K1_WAVES 8

#define K2_PPT 16
#define K2_WAVES 8

// ---------------- DPP reductions ------------------------------------------------------
#define DPP_STEP_UMIN(ctrl, rmask)                                                 \
    { unsigned t = (unsigned)__builtin_amdgcn_update_dpp(                          \
            (int)v, (int)v, ctrl, rmask, 0xF, false);                              \
      v = (t < v) ? t : v; }

__device__ __forceinline__ unsigned wave_umin32(unsigned v) {
    DPP_STEP_UMIN(0x111, 0xF);
    DPP_STEP_UMIN(0x112, 0xF);
    DPP_STEP_UMIN(0x114, 0xF);
    DPP_STEP_UMIN(0x118, 0xF);
    DPP_STEP_UMIN(0x142, 0xA);
    DPP_STEP_UMIN(0x143, 0xC);
    return v;   // lane 63 valid
}

#define DPP_STEP_FMAX(ctrl, rmask)                                                 \
    v = fmaxf(v, __int_as_float(__builtin_amdgcn_update_dpp(                       \
            __float_as_int(v), __float_as_int(v), ctrl, rmask, 0xF, false)))

__device__ __forceinline__ float wave_fmax(float v) {
    DPP_STEP_FMAX(0x111, 0xF);
    DPP_STEP_FMAX(0x112, 0xF);
    DPP_STEP_FMAX(0x114, 0xF);
    DPP_STEP_FMAX(0x118, 0xF);
    DPP_STEP_FMAX(0x142, 0xA);
    DPP_STEP_FMAX(0x143, 0xC);
    return v;   // lane 63 valid
}

#define U64_DPP_STEP(ctrl, rmask, CMPOP)                                           \
    { unsigned lo_ = (unsigned)v, hi_ = (unsigned)(v >> 32);                       \
      unsigned olo = (unsigned)__builtin_amdgcn_update_dpp((int)lo_, (int)lo_, ctrl, rmask, 0xF, false); \
      unsigned ohi = (unsigned)__builtin_amdgcn_update_dpp((int)hi_, (int)hi_, ctrl, rmask, 0xF, false); \
      unsigned long long o = ((unsigned long long)ohi << 32) | olo;                \
      if (o CMPOP v) v = o; }

__device__ __forceinline__ int rdlane63_i(int v) {
    return __builtin_amdgcn_readlane(v, 63);
}

// Exact (no-FMA) squared distance in numpy's evaluation order: (dx^2 + dy^2) + dz^2
__device__ __forceinline__ float sq_dist(float x, float y, float z,
                                         float cx, float cy, float cz) {
    float dx = __fsub_rn(x, cx);
    float dy = __fsub_rn(y, cy);
    float dz = __fsub_rn(z, cz);
    return __fadd_rn(__fadd_rn(__fmul_rn(dx, dx), __fmul_rn(dy, dy)), __fmul_rn(dz, dz));
}

__device__ __forceinline__ unsigned fxform(unsigned u) {
    return u ^ (unsigned)(((int)u >> 31) | 0x80000000);
}

// bitonic sort (ascending) of an N-element register array of u64
template<int N>
__device__ __forceinline__ void bitonic_sort(unsigned long long* a) {
#pragma unroll
    for (int k = 2; k <= N; k <<= 1) {
#pragma unroll
        for (int j = k >> 1; j > 0; j >>= 1) {
#pragma unroll
            for (int i = 0; i < N; ++i) {
                int ixj = i ^ j;
                if (ixj > i) {
                    bool up = ((i & k) == 0);
                    unsigned long long x = a[i], y = a[ixj];
                    bool sw = up ? (x > y) : (x < y);
                    if (sw) { a[i] = y; a[ixj] = x; }
                }
            }
        }
    }
}

// LDS overlay: fps needs lx/ly/lz + part; knn needs wtop + nlist. 96.5 KB -> 1 block/CU.
union SharedLDS {
    struct {
        float lx[N_PTS]; float ly[N_PTS]; float lz[N_PTS];   // 96 KB
        unsigned part[2][K1_WAVES][8];
    } f;
    struct {
        unsigned long long wtop[K2_WAVES][GSIZE];            // 2 KB
        unsigned nlist[GSIZE];
    } k;
};

// ---------------- fused kernel --------------------------------------------------------
// Blocks 0..7: FPS for batch b (R9 512t/16ppt body — fits the 88-VGPR budget, no spill).
// After writing group it, release-store progress[b]=it+1 (agent scope).
// Blocks 8..255: kNN workers; consume groups in ready-order idx=g*8+b, stride 248;
// acquire-spin on progress[b] > g, then the R10 knn body.
extern "C" __global__ __launch_bounds__(THREADS, 1) void fused_kernel(
    const float* __restrict__ xyz, float* __restrict__ out,
    int* __restrict__ fps_idx, int* __restrict__ progress)
{
    __shared__ SharedLDS S;
    const int bid = blockIdx.x;
    const int tid = threadIdx.x;
    const int lane = tid & 63;
    const int wid  = tid >> 6;

    if (bid < FPS_BLOCKS) {
        // =========================== FPS (batch = bid) ===============================
        const int b = bid;
        const float* base = xyz + (size_t)b * N_PTS * 6;
        const float4* b4 = (const float4*)base;

        // 16 consecutive points per thread via 24 float4 loads (all bytes used)
        float sx[K1_PPT], sy[K1_PPT], sz[K1_PPT], dd[K1_PPT];
        const int tb = tid * 24;
#pragma unroll
        for (int c = 0; c < 4; ++c) {
            float4 f0 = b4[tb + c * 6 + 0];
            float4 f1 = b4[tb + c * 6 + 1];
            float4 f2 = b4[tb + c * 6 + 2];
            float4 f3 = b4[tb + c * 6 + 3];
            float4 f4 = b4[tb + c * 6 + 4];
            float4 f5 = b4[tb + c * 6 + 5];
            sx[c*4+0] = f0.x; sy[c*4+0] = f0.y; sz[c*4+0] = f0.z;
            sx[c*4+1] = f1.z; sy[c*4+1] = f1.w; sz[c*4+1] = f2.x;
            sx[c*4+2] = f3.x; sy[c*4+2] = f3.y; sz[c*4+2] = f3.z;
            sx[c*4+3] = f4.z; sy[c*4+3] = f4.w; sz[c*4+3] = f5.x;
        }
        // swizzled staging: point p = tid*16+i at A(p) = (i<<9)+tid (conflict-free)
#pragma unroll
        for (int i = 0; i < K1_PPT; ++i) {
            int a = (i << 9) + tid;
            S.f.lx[a] = sx[i]; S.f.ly[a] = sy[i]; S.f.lz[a] = sz[i];
            dd[i] = BIGF;
        }
        __syncthreads();

        unsigned cur = 0;
        float cx = S.f.lx[0], cy = S.f.ly[0], cz = S.f.lz[0];   // point 0: A(0)=0

        for (int it = 0; it < NGROUP; ++it) {
            if (tid == 0) {
                fps_idx[b * NGROUP + it] = (int)cur;
                __hip_atomic_store(&progress[b], it + 1,
                                   __ATOMIC_RELEASE, __HIP_MEMORY_SCOPE_AGENT);
            }
            if (it == NGROUP - 1) break;

            // min-update + inline first-max tracking (ascending i == ascending idx)
            float bestd = -1.0f;
            unsigned besti = 0;
#pragma unroll
            for (int i = 0; i < K1_PPT; ++i) {
                float d = sq_dist(sx[i], sy[i], sz[i], cx, cy, cz);
                dd[i] = fminf(dd[i], d);
                bool gt = dd[i] > bestd;
                bestd = gt ? dd[i] : bestd;
                besti = gt ? (unsigned)i : besti;
            }
            unsigned bestp = (unsigned)tid * K1_PPT + besti;

            // wave argmax: f32 DPP max, then first tied lane (= smallest global index)
            float wm = __int_as_float(rdlane63_i(__float_as_int(wave_fmax(bestd))));
            unsigned long long bal = __ballot(bestd == wm);
            int L = (int)(__ffsll((long long)bal) - 1);
            unsigned widx = (unsigned)__builtin_amdgcn_readlane((int)bestp, L);

            if (lane == 0) {
                int wa = (int)(((widx & 15u) << 9) + (widx >> 4));
                unsigned* pp = S.f.part[it & 1][wid];
                pp[0] = 0xFFFFFFFFu - widx;
                pp[1] = __float_as_uint(wm);
                pp[2] = __float_as_uint(S.f.lx[wa]);
                pp[3] = __float_as_uint(S.f.ly[wa]);
                pp[4] = __float_as_uint(S.f.lz[wa]);
            }
            __syncthreads();

            // block reduce over 8 partials: lanes 0..7, max valid in lane 7
            const unsigned* pp = S.f.part[it & 1][lane & 7];
            unsigned kl = pp[0], kh = pp[1];
            float xx = __uint_as_float(pp[2]);
            float yy = __uint_as_float(pp[3]);
            float zz = __uint_as_float(pp[4]);
            unsigned long long v = ((unsigned long long)kh << 32) | kl;
            U64_DPP_STEP(0x111, 0xF, >);
            U64_DPP_STEP(0x112, 0xF, >);
            U64_DPP_STEP(0x114, 0xF, >);
            unsigned wkl = (unsigned)__builtin_amdgcn_readlane((int)(unsigned)v, 7);
            cur = 0xFFFFFFFFu - wkl;
            int W = (int)(cur >> 10);   // 1024 pts/wave -> winning wave id
            cx = __int_as_float(__builtin_amdgcn_readlane(__float_as_int(xx), W));
            cy = __int_as_float(__builtin_amdgcn_readlane(__float_as_int(yy), W));
            cz = __int_as_float(__builtin_amdgcn_readlane(__float_as_int(zz), W));
        }
        return;
    }

    // ============================= kNN worker blocks =================================
    const int OFF1 = N_B * NGROUP * GSIZE * 3;   // neigh_attr
    const int OFF2 = 2 * OFF1;                   // center
    const int OFF3 = OFF2 + N_B * NGROUP * 3;    // center_attribute

    for (int idx = bid - FPS_BLOCKS; idx < N_B * NGROUP; idx += KNN_BLOCKS) {
        const int g = idx >> 3;
        const int b = idx & 7;
        const float* base = xyz + (size_t)b * N_PTS * 6;

        if (tid == 0) {
            while (__hip_atomic_load(&progress[b], __ATOMIC_ACQUIRE,
                                     __HIP_MEMORY_SCOPE_AGENT) <= g)
                __builtin_amdgcn_s_sleep(2);
        }
        __syncthreads();

        const int q  = fps_idx[b * NGROUP + g];
        const int qq = __builtin_amdgcn_readfirstlane(q);
        const float cx = base[qq * 6 + 0];
        const float cy = base[qq * 6 + 1];
        const float cz = base[qq * 6 + 2];
        // ||c||^2: separate square, left-assoc add, NO FMA
        const float cn = __fadd_rn(__fadd_rn(__fmul_rn(cx, cx), __fmul_rn(cy, cy)),
                                   __fmul_rn(cz, cz));

        const float4* b4 = (const float4*)base;
        const int tb = tid * 24;

        unsigned long long keys[K2_PPT];

#pragma unroll
        for (int c = 0; c < 4; ++c) {
            float4 f0 = b4[tb + c * 6 + 0];
            float4 f1 = b4[tb + c * 6 + 1];
            float4 f2 = b4[tb + c * 6 + 2];
            float4 f3 = b4[tb + c * 6 + 3];
            float4 f4 = b4[tb + c * 6 + 4];
            float4 f5 = b4[tb + c * 6 + 5];
            float X[4] = {f0.x, f1.z, f3.x, f4.z};
            float Y[4] = {f0.y, f1.w, f3.y, f4.w};
            float Z[4] = {f0.z, f2.x, f3.z, f5.x};
#pragma unroll
            for (int j = 0; j < 4; ++j) {
                float x = X[j], y = Y[j], z = Z[j];
                float xn  = __fadd_rn(__fadd_rn(__fmul_rn(x, x), __fmul_rn(y, y)), __fmul_rn(z, z));
                float dot = __fmul_rn(cx, x);
                dot = __fmaf_rn(cy, y, dot);
                dot = __fmaf_rn(cz, z, dot);
                float d2  = __fadd_rn(__fsub_rn(cn, __fmul_rn(2.0f, dot)), xn);
                int p = tid * K2_PPT + c * 4 + j;
                keys[c * 4 + j] =
                    ((unsigned long long)fxform(__float_as_uint(d2)) << 32) | (unsigned)p;
            }
        }

        bitonic_sort<K2_PPT>(keys);

        // per-wave top-32 extraction (ascending into wtop[wid])
        {
            unsigned long long cand = keys[0];
            unsigned w = 0;
            for (int r = 0; r < GSIZE; ++r) {
                unsigned ch = (unsigned)(cand >> 32);
                unsigned whd = (unsigned)rdlane63_i((int)wave_umin32(ch));
                unsigned long long bal = __ballot(ch == whd);
                unsigned wl;
                if (__popcll(bal) == 1) {
                    int L = (int)(__ffsll((long long)bal) - 1);
                    wl = (unsigned)__builtin_amdgcn_readlane((int)(unsigned)cand, L);
                } else {
                    unsigned cl = (ch == whd) ? (unsigned)cand : 0xFFFFFFFFu;
                    wl = (unsigned)rdlane63_i((int)wave_umin32(cl));
                }
                unsigned long long wkey = ((unsigned long long)whd << 32) | wl;
                if (lane == 0) S.k.wtop[wid][r] = wkey;
                if (cand == wkey) {   // exactly one lane (keys unique)
                    ++w;
                    unsigned long long nc;
                    if (w < 4) {
                        nc = (w == 1) ? keys[1] : (w == 2) ? keys[2] : keys[3];
                    } else if (w < K2_PPT) {
                        nc = keys[4];
#pragma unroll
                        for (int j = 5; j < K2_PPT; ++j) nc = (w == (unsigned)j) ? keys[j] : nc;
                    } else {
                        nc = ~0ull;
                    }
                    cand = nc;
                }
            }
        }
        __syncthreads();

        // parallel rank-merge: 256 threads, one candidate each
        if (tid < K2_WAVES * GSIZE) {
            const int w8 = tid >> 5, i = tid & 31;
            unsigned long long e = S.k.wtop[w8][i];
            int rank = 0;
#pragma unroll
            for (int l = 0; l < K2_WAVES; ++l) {
                const unsigned long long* arr = S.k.wtop[l];
                int lo = 0;
                if (arr[15]     < e) lo = 16;
                if (arr[lo + 7] < e) lo += 8;
                if (arr[lo + 3] < e) lo += 4;
                if (arr[lo + 1] < e) lo += 2;
                if (arr[lo]     < e) lo += 1;
                rank += lo;
            }
            if (rank < GSIZE) S.k.nlist[rank] = (unsigned)e;
        }
        __syncthreads();

        // ---- outputs ----
        if (tid < GSIZE) {
            unsigned p = S.k.nlist[tid];
            float x  = base[p * 6 + 0];
            float y  = base[p * 6 + 1];
            float z  = base[p * 6 + 2];
            float a0 = base[p * 6 + 3];
            float a1 = base[p * 6 + 4];
            float a2 = base[p * 6 + 5];
            size_t o = ((size_t)(b * NGROUP + g) * GSIZE + tid) * 3;
            out[o + 0] = __fsub_rn(x, cx);
            out[o + 1] = __fsub_rn(y, cy);
            out[o + 2] = __fsub_rn(z, cz);
            out[OFF1 + o + 0] = a0;
            out[OFF1 + o + 1] = a1;
            out[OFF1 + o + 2] = a2;
        } else if (tid == GSIZE) {
            size_t o = (size_t)(b * NGROUP + g) * 3;
            out[OFF2 + o + 0] = cx;
            out[OFF2 + o + 1] = cy;
            out[OFF2 + o + 2] = cz;
            out[OFF3 + o + 0] = base[qq * 6 + 3];
            out[OFF3 + o + 1] = base[qq * 6 + 4];
            out[OFF3 + o + 2] = base[qq * 6 + 5];
        }
        __syncthreads();   // protect S.k reuse across loop iterations
    }
}

extern "C" void kernel_launch(void* const* d_in, const int* in_sizes, int n_in,
                              void* d_out, int out_size, void* d_ws, size_t ws_size,
                              hipStream_t stream) {
    const float* xyz = (const float*)d_in[0];
    float* out = (float*)d_out;
    int* fps_idx  = (int*)d_ws;                          // 16 KB
    int* progress = (int*)((char*)d_ws + 16384);         // 8 ints; 0xAA poison < 0 => spin

    fused_kernel<<<TOT_BLOCKS, THREADS, 0, stream>>>(xyz, out, fps_idx, progress);
}

// Round 15
// 605.052 us; speedup vs baseline: 1.8765x; 1.6255x over previous
//
#include <hip/hip_runtime.h>
#include <stdint.h>

#define N_PTS 8192
#define N_B 8
#define NGROUP 512
#define GSIZE 32
#define BIGF 1e10f

#define THREADS 512
#define TOT_BLOCKS 256
#define FPS_BLOCKS 8
#define KNN_BLOCKS (TOT_BLOCKS - FPS_BLOCKS)   // 248

#define K1_PPT 16            // fps points per thread (fits 88-VGPR budget: R9/R14 evidence)
#define K1_WAVES 8
#define PUB_CHUNK 16         // publish progress every 16 groups (release cost off hot path)

#define K2_PPT 16
#define K2_WAVES 8

// ---------------- DPP reductions ------------------------------------------------------
#define DPP_STEP_UMIN(ctrl, rmask)                                                 \
    { unsigned t = (unsigned)__builtin_amdgcn_update_dpp(                          \
            (int)v, (int)v, ctrl, rmask, 0xF, false);                              \
      v = (t < v) ? t : v; }

__device__ __forceinline__ unsigned wave_umin32(unsigned v) {
    DPP_STEP_UMIN(0x111, 0xF);
    DPP_STEP_UMIN(0x112, 0xF);
    DPP_STEP_UMIN(0x114, 0xF);
    DPP_STEP_UMIN(0x118, 0xF);
    DPP_STEP_UMIN(0x142, 0xA);
    DPP_STEP_UMIN(0x143, 0xC);
    return v;   // lane 63 valid
}

#define DPP_STEP_FMAX(ctrl, rmask)                                                 \
    v = fmaxf(v, __int_as_float(__builtin_amdgcn_update_dpp(                       \
            __float_as_int(v), __float_as_int(v), ctrl, rmask, 0xF, false)))

__device__ __forceinline__ float wave_fmax(float v) {
    DPP_STEP_FMAX(0x111, 0xF);
    DPP_STEP_FMAX(0x112, 0xF);
    DPP_STEP_FMAX(0x114, 0xF);
    DPP_STEP_FMAX(0x118, 0xF);
    DPP_STEP_FMAX(0x142, 0xA);
    DPP_STEP_FMAX(0x143, 0xC);
    return v;   // lane 63 valid
}

#define U64_DPP_STEP(ctrl, rmask, CMPOP)                                           \
    { unsigned lo_ = (unsigned)v, hi_ = (unsigned)(v >> 32);                       \
      unsigned olo = (unsigned)__builtin_amdgcn_update_dpp((int)lo_, (int)lo_, ctrl, rmask, 0xF, false); \
      unsigned ohi = (unsigned)__builtin_amdgcn_update_dpp((int)hi_, (int)hi_, ctrl, rmask, 0xF, false); \
      unsigned long long o = ((unsigned long long)ohi << 32) | olo;                \
      if (o CMPOP v) v = o; }

__device__ __forceinline__ int rdlane63_i(int v) {
    return __builtin_amdgcn_readlane(v, 63);
}

// Exact (no-FMA) squared distance in numpy's evaluation order: (dx^2 + dy^2) + dz^2
__device__ __forceinline__ float sq_dist(float x, float y, float z,
                                         float cx, float cy, float cz) {
    float dx = __fsub_rn(x, cx);
    float dy = __fsub_rn(y, cy);
    float dz = __fsub_rn(z, cz);
    return __fadd_rn(__fadd_rn(__fmul_rn(dx, dx), __fmul_rn(dy, dy)), __fmul_rn(dz, dz));
}

__device__ __forceinline__ unsigned fxform(unsigned u) {
    return u ^ (unsigned)(((int)u >> 31) | 0x80000000);
}

// bitonic sort (ascending) of an N-element register array of u64
template<int N>
__device__ __forceinline__ void bitonic_sort(unsigned long long* a) {
#pragma unroll
    for (int k = 2; k <= N; k <<= 1) {
#pragma unroll
        for (int j = k >> 1; j > 0; j >>= 1) {
#pragma unroll
            for (int i = 0; i < N; ++i) {
                int ixj = i ^ j;
                if (ixj > i) {
                    bool up = ((i & k) == 0);
                    unsigned long long x = a[i], y = a[ixj];
                    bool sw = up ? (x > y) : (x < y);
                    if (sw) { a[i] = y; a[ixj] = x; }
                }
            }
        }
    }
}

// LDS overlay: fps needs lx/ly/lz + part; knn needs wtop + nlist. 96.5 KB -> 1 block/CU.
union SharedLDS {
    struct {
        float lx[N_PTS]; float ly[N_PTS]; float lz[N_PTS];   // 96 KB
        unsigned part[2][K1_WAVES][8];
    } f;
    struct {
        unsigned long long wtop[K2_WAVES][GSIZE];            // 2 KB
        unsigned nlist[GSIZE];
    } k;
};

// ---------------- fused kernel --------------------------------------------------------
// Blocks 0..7: FPS (R9 512t/16ppt body). fps_idx written with RELAXED agent atomics
// (no waits, no cache ops); progress[b] release-published every PUB_CHUNK groups.
// Blocks 8..255: kNN workers; RELAXED spin (no buffer_inv -> caches stay warm),
// __syncthreads() as reorder barrier, RELAXED atomic read of fps_idx.
extern "C" __global__ __launch_bounds__(THREADS, 1) void fused_kernel(
    const float* __restrict__ xyz, float* __restrict__ out,
    int* __restrict__ fps_idx, int* __restrict__ progress)
{
    __shared__ SharedLDS S;
    const int bid = blockIdx.x;
    const int tid = threadIdx.x;
    const int lane = tid & 63;
    const int wid  = tid >> 6;

    if (bid < FPS_BLOCKS) {
        // =========================== FPS (batch = bid) ===============================
        const int b = bid;
        const float* base = xyz + (size_t)b * N_PTS * 6;
        const float4* b4 = (const float4*)base;

        float sx[K1_PPT], sy[K1_PPT], sz[K1_PPT], dd[K1_PPT];
        const int tb = tid * 24;
#pragma unroll
        for (int c = 0; c < 4; ++c) {
            float4 f0 = b4[tb + c * 6 + 0];
            float4 f1 = b4[tb + c * 6 + 1];
            float4 f2 = b4[tb + c * 6 + 2];
            float4 f3 = b4[tb + c * 6 + 3];
            float4 f4 = b4[tb + c * 6 + 4];
            float4 f5 = b4[tb + c * 6 + 5];
            sx[c*4+0] = f0.x; sy[c*4+0] = f0.y; sz[c*4+0] = f0.z;
            sx[c*4+1] = f1.z; sy[c*4+1] = f1.w; sz[c*4+1] = f2.x;
            sx[c*4+2] = f3.x; sy[c*4+2] = f3.y; sz[c*4+2] = f3.z;
            sx[c*4+3] = f4.z; sy[c*4+3] = f4.w; sz[c*4+3] = f5.x;
        }
        // swizzled staging: point p = tid*16+i at A(p) = (i<<9)+tid (conflict-free)
#pragma unroll
        for (int i = 0; i < K1_PPT; ++i) {
            int a = (i << 9) + tid;
            S.f.lx[a] = sx[i]; S.f.ly[a] = sy[i]; S.f.lz[a] = sz[i];
            dd[i] = BIGF;
        }
        __syncthreads();

        unsigned cur = 0;
        float cx = S.f.lx[0], cy = S.f.ly[0], cz = S.f.lz[0];   // point 0: A(0)=0

        for (int it = 0; it < NGROUP; ++it) {
            if (tid == 0) {
                // fire-and-forget to coherence point; no cache maintenance
                __hip_atomic_store(&fps_idx[b * NGROUP + it], (int)cur,
                                   __ATOMIC_RELAXED, __HIP_MEMORY_SCOPE_AGENT);
                if ((it & (PUB_CHUNK - 1)) == (PUB_CHUNK - 1) || it == NGROUP - 1) {
                    // release: drains prior relaxed stores first, then publish
                    __hip_atomic_store(&progress[b], it + 1,
                                       __ATOMIC_RELEASE, __HIP_MEMORY_SCOPE_AGENT);
                }
            }
            if (it == NGROUP - 1) break;

            // min-update + inline first-max tracking (ascending i == ascending idx)
            float bestd = -1.0f;
            unsigned besti = 0;
#pragma unroll
            for (int i = 0; i < K1_PPT; ++i) {
                float d = sq_dist(sx[i], sy[i], sz[i], cx, cy, cz);
                dd[i] = fminf(dd[i], d);
                bool gt = dd[i] > bestd;
                bestd = gt ? dd[i] : bestd;
                besti = gt ? (unsigned)i : besti;
            }
            unsigned bestp = (unsigned)tid * K1_PPT + besti;

            // wave argmax: f32 DPP max, then first tied lane (= smallest global index)
            float wm = __int_as_float(rdlane63_i(__float_as_int(wave_fmax(bestd))));
            unsigned long long bal = __ballot(bestd == wm);
            int L = (int)(__ffsll((long long)bal) - 1);
            unsigned widx = (unsigned)__builtin_amdgcn_readlane((int)bestp, L);

            if (lane == 0) {
                int wa = (int)(((widx & 15u) << 9) + (widx >> 4));
                unsigned* pp = S.f.part[it & 1][wid];
                pp[0] = 0xFFFFFFFFu - widx;
                pp[1] = __float_as_uint(wm);
                pp[2] = __float_as_uint(S.f.lx[wa]);
                pp[3] = __float_as_uint(S.f.ly[wa]);
                pp[4] = __float_as_uint(S.f.lz[wa]);
            }
            __syncthreads();

            // block reduce over 8 partials: lanes 0..7, max valid in lane 7
            const unsigned* pp = S.f.part[it & 1][lane & 7];
            unsigned kl = pp[0], kh = pp[1];
            float xx = __uint_as_float(pp[2]);
            float yy = __uint_as_float(pp[3]);
            float zz = __uint_as_float(pp[4]);
            unsigned long long v = ((unsigned long long)kh << 32) | kl;
            U64_DPP_STEP(0x111, 0xF, >);
            U64_DPP_STEP(0x112, 0xF, >);
            U64_DPP_STEP(0x114, 0xF, >);
            unsigned wkl = (unsigned)__builtin_amdgcn_readlane((int)(unsigned)v, 7);
            cur = 0xFFFFFFFFu - wkl;
            int W = (int)(cur >> 10);   // 1024 pts/wave -> winning wave id
            cx = __int_as_float(__builtin_amdgcn_readlane(__float_as_int(xx), W));
            cy = __int_as_float(__builtin_amdgcn_readlane(__float_as_int(yy), W));
            cz = __int_as_float(__builtin_amdgcn_readlane(__float_as_int(zz), W));
        }
        return;
    }

    // ============================= kNN worker blocks =================================
    const int OFF1 = N_B * NGROUP * GSIZE * 3;   // neigh_attr
    const int OFF2 = 2 * OFF1;                   // center
    const int OFF3 = OFF2 + N_B * NGROUP * 3;    // center_attribute

    for (int idx = bid - FPS_BLOCKS; idx < N_B * NGROUP; idx += KNN_BLOCKS) {
        const int g = idx >> 3;
        const int b = idx & 7;
        const float* base = xyz + (size_t)b * N_PTS * 6;

        if (tid == 0) {
            // relaxed spin: no cache invalidation, caches stay warm
            while (__hip_atomic_load(&progress[b], __ATOMIC_RELAXED,
                                     __HIP_MEMORY_SCOPE_AGENT) <= g)
                __builtin_amdgcn_s_sleep(32);
        }
        __syncthreads();   // reorder barrier between spin and data read

        const int q  = __hip_atomic_load(&fps_idx[b * NGROUP + g],
                                         __ATOMIC_RELAXED, __HIP_MEMORY_SCOPE_AGENT);
        const int qq = __builtin_amdgcn_readfirstlane(q);
        const float cx = base[qq * 6 + 0];
        const float cy = base[qq * 6 + 1];
        const float cz = base[qq * 6 + 2];
        // ||c||^2: separate square, left-assoc add, NO FMA
        const float cn = __fadd_rn(__fadd_rn(__fmul_rn(cx, cx), __fmul_rn(cy, cy)),
                                   __fmul_rn(cz, cz));

        const float4* b4 = (const float4*)base;
        const int tb = tid * 24;

        unsigned long long keys[K2_PPT];

#pragma unroll
        for (int c = 0; c < 4; ++c) {
            float4 f0 = b4[tb + c * 6 + 0];
            float4 f1 = b4[tb + c * 6 + 1];
            float4 f2 = b4[tb + c * 6 + 2];
            float4 f3 = b4[tb + c * 6 + 3];
            float4 f4 = b4[tb + c * 6 + 4];
            float4 f5 = b4[tb + c * 6 + 5];
            float X[4] = {f0.x, f1.z, f3.x, f4.z};
            float Y[4] = {f0.y, f1.w, f3.y, f4.w};
            float Z[4] = {f0.z, f2.x, f3.z, f5.x};
#pragma unroll
            for (int j = 0; j < 4; ++j) {
                float x = X[j], y = Y[j], z = Z[j];
                float xn  = __fadd_rn(__fadd_rn(__fmul_rn(x, x), __fmul_rn(y, y)), __fmul_rn(z, z));
                float dot = __fmul_rn(cx, x);
                dot = __fmaf_rn(cy, y, dot);
                dot = __fmaf_rn(cz, z, dot);
                float d2  = __fadd_rn(__fsub_rn(cn, __fmul_rn(2.0f, dot)), xn);
                int p = tid * K2_PPT + c * 4 + j;
                keys[c * 4 + j] =
                    ((unsigned long long)fxform(__float_as_uint(d2)) << 32) | (unsigned)p;
            }
        }

        bitonic_sort<K2_PPT>(keys);

        // per-wave top-32 extraction (ascending into wtop[wid])
        {
            unsigned long long cand = keys[0];
            unsigned w = 0;
            for (int r = 0; r < GSIZE; ++r) {
                unsigned ch = (unsigned)(cand >> 32);
                unsigned whd = (unsigned)rdlane63_i((int)wave_umin32(ch));
                unsigned long long bal = __ballot(ch == whd);
                unsigned wl;
                if (__popcll(bal) == 1) {
                    int L = (int)(__ffsll((long long)bal) - 1);
                    wl = (unsigned)__builtin_amdgcn_readlane((int)(unsigned)cand, L);
                } else {
                    unsigned cl = (ch == whd) ? (unsigned)cand : 0xFFFFFFFFu;
                    wl = (unsigned)rdlane63_i((int)wave_umin32(cl));
                }
                unsigned long long wkey = ((unsigned long long)whd << 32) | wl;
                if (lane == 0) S.k.wtop[wid][r] = wkey;
                if (cand == wkey) {   // exactly one lane (keys unique)
                    ++w;
                    unsigned long long nc;
                    if (w < 4) {
                        nc = (w == 1) ? keys[1] : (w == 2) ? keys[2] : keys[3];
                    } else if (w < K2_PPT) {
                        nc = keys[4];
#pragma unroll
                        for (int j = 5; j < K2_PPT; ++j) nc = (w == (unsigned)j) ? keys[j] : nc;
                    } else {
                        nc = ~0ull;
                    }
                    cand = nc;
                }
            }
        }
        __syncthreads();

        // parallel rank-merge: 256 threads, one candidate each
        if (tid < K2_WAVES * GSIZE) {
            const int w8 = tid >> 5, i = tid & 31;
            unsigned long long e = S.k.wtop[w8][i];
            int rank = 0;
#pragma unroll
            for (int l = 0; l < K2_WAVES; ++l) {
                const unsigned long long* arr = S.k.wtop[l];
                int lo = 0;
                if (arr[15]     < e) lo = 16;
                if (arr[lo + 7] < e) lo += 8;
                if (arr[lo + 3] < e) lo += 4;
                if (arr[lo + 1] < e) lo += 2;
                if (arr[lo]     < e) lo += 1;
                rank += lo;
            }
            if (rank < GSIZE) S.k.nlist[rank] = (unsigned)e;
        }
        __syncthreads();

        // ---- outputs ----
        if (tid < GSIZE) {
            unsigned p = S.k.nlist[tid];
            float x  = base[p * 6 + 0];
            float y  = base[p * 6 + 1];
            float z  = base[p * 6 + 2];
            float a0 = base[p * 6 + 3];
            float a1 = base[p * 6 + 4];
            float a2 = base[p * 6 + 5];
            size_t o = ((size_t)(b * NGROUP + g) * GSIZE + tid) * 3;
            out[o + 0] = __fsub_rn(x, cx);
            out[o + 1] = __fsub_rn(y, cy);
            out[o + 2] = __fsub_rn(z, cz);
            out[OFF1 + o + 0] = a0;
            out[OFF1 + o + 1] = a1;
            out[OFF1 + o + 2] = a2;
        } else if (tid == GSIZE) {
            size_t o = (size_t)(b * NGROUP + g) * 3;
            out[OFF2 + o + 0] = cx;
            out[OFF2 + o + 1] = cy;
            out[OFF2 + o + 2] = cz;
            out[OFF3 + o + 0] = base[qq * 6 + 3];
            out[OFF3 + o + 1] = base[qq * 6 + 4];
            out[OFF3 + o + 2] = base[qq * 6 + 5];
        }
        __syncthreads();   // protect S.k reuse across loop iterations
    }
}

extern "C" void kernel_launch(void* const* d_in, const int* in_sizes, int n_in,
                              void* d_out, int out_size, void* d_ws, size_t ws_size,
                              hipStream_t stream) {
    const float* xyz = (const float*)d_in[0];
    float* out = (float*)d_out;
    int* fps_idx  = (int*)d_ws;                          // 16 KB
    int* progress = (int*)((char*)d_ws + 16384);         // 8 ints; 0xAA poison < 0 => spin

    fused_kernel<<<TOT_BLOCKS, THREADS, 0, stream>>>(xyz, out, fps_idx, progress);
}

// Round 16
// 600.344 us; speedup vs baseline: 1.8912x; 1.0078x over previous
//
#include <hip/hip_runtime.h>
#include <stdint.h>

#define N_PTS 8192
#define N_B 8
#define NGROUP 512
#define GSIZE 32
#define BIGF 1e10f

#define THREADS 512
#define TOT_BLOCKS 256
#define FPS_BLOCKS 8
#define KNN_BLOCKS (TOT_BLOCKS - FPS_BLOCKS)   // 248

#define K1_PPT 16            // fps points per thread (fits 88-VGPR budget cleanly)
#define K1_WAVES 8

#define K2_PPT 16
#define K2_WAVES 8

// ---------------- DPP reductions ------------------------------------------------------
#define DPP_STEP_UMIN(ctrl, rmask)                                                 \
    { unsigned t = (unsigned)__builtin_amdgcn_update_dpp(                          \
            (int)v, (int)v, ctrl, rmask, 0xF, false);                              \
      v = (t < v) ? t : v; }

__device__ __forceinline__ unsigned wave_umin32(unsigned v) {
    DPP_STEP_UMIN(0x111, 0xF);
    DPP_STEP_UMIN(0x112, 0xF);
    DPP_STEP_UMIN(0x114, 0xF);
    DPP_STEP_UMIN(0x118, 0xF);
    DPP_STEP_UMIN(0x142, 0xA);
    DPP_STEP_UMIN(0x143, 0xC);
    return v;   // lane 63 valid
}

#define DPP_STEP_FMAX(ctrl, rmask)                                                 \
    v = fmaxf(v, __int_as_float(__builtin_amdgcn_update_dpp(                       \
            __float_as_int(v), __float_as_int(v), ctrl, rmask, 0xF, false)))

__device__ __forceinline__ float wave_fmax(float v) {
    DPP_STEP_FMAX(0x111, 0xF);
    DPP_STEP_FMAX(0x112, 0xF);
    DPP_STEP_FMAX(0x114, 0xF);
    DPP_STEP_FMAX(0x118, 0xF);
    DPP_STEP_FMAX(0x142, 0xA);
    DPP_STEP_FMAX(0x143, 0xC);
    return v;   // lane 63 valid
}

#define U64_DPP_STEP(ctrl, rmask, CMPOP)                                           \
    { unsigned lo_ = (unsigned)v, hi_ = (unsigned)(v >> 32);                       \
      unsigned olo = (unsigned)__builtin_amdgcn_update_dpp((int)lo_, (int)lo_, ctrl, rmask, 0xF, false); \
      unsigned ohi = (unsigned)__builtin_amdgcn_update_dpp((int)hi_, (int)hi_, ctrl, rmask, 0xF, false); \
      unsigned long long o = ((unsigned long long)ohi << 32) | olo;                \
      if (o CMPOP v) v = o; }

__device__ __forceinline__ int rdlane63_i(int v) {
    return __builtin_amdgcn_readlane(v, 63);
}

// Exact (no-FMA) squared distance in numpy's evaluation order: (dx^2 + dy^2) + dz^2
__device__ __forceinline__ float sq_dist(float x, float y, float z,
                                         float cx, float cy, float cz) {
    float dx = __fsub_rn(x, cx);
    float dy = __fsub_rn(y, cy);
    float dz = __fsub_rn(z, cz);
    return __fadd_rn(__fadd_rn(__fmul_rn(dx, dx), __fmul_rn(dy, dy)), __fmul_rn(dz, dz));
}

__device__ __forceinline__ unsigned fxform(unsigned u) {
    return u ^ (unsigned)(((int)u >> 31) | 0x80000000);
}

// bitonic sort (ascending) of an N-element register array of u64
template<int N>
__device__ __forceinline__ void bitonic_sort(unsigned long long* a) {
#pragma unroll
    for (int k = 2; k <= N; k <<= 1) {
#pragma unroll
        for (int j = k >> 1; j > 0; j >>= 1) {
#pragma unroll
            for (int i = 0; i < N; ++i) {
                int ixj = i ^ j;
                if (ixj > i) {
                    bool up = ((i & k) == 0);
                    unsigned long long x = a[i], y = a[ixj];
                    bool sw = up ? (x > y) : (x < y);
                    if (sw) { a[i] = y; a[ixj] = x; }
                }
            }
        }
    }
}

// LDS overlay: fps needs lx/ly/lz + part; knn needs wtop + nlist + qshare.
union SharedLDS {
    struct {
        float lx[N_PTS]; float ly[N_PTS]; float lz[N_PTS];   // 96 KB
        unsigned part[2][K1_WAVES][8];
    } f;
    struct {
        unsigned long long wtop[K2_WAVES][GSIZE];            // 2 KB
        unsigned nlist[GSIZE];
        int qshare;
    } k;
};

// ---------------- fused kernel --------------------------------------------------------
// Blocks 0..7: FPS (512t/16ppt body). fps_idx written once per group with a RELAXED
// agent atomic store — the datum is its own ready-flag (poison 0xAA < 0, indices >= 0).
// Blocks 8..255: kNN workers; tid0 RELAXED-atomic-spins on fps_idx[b,g] >= 0 (L2 read,
// no cache invalidation), LDS-broadcasts it, __syncthreads() orders the block.
extern "C" __global__ __launch_bounds__(THREADS, 1) void fused_kernel(
    const float* __restrict__ xyz, float* __restrict__ out,
    int* __restrict__ fps_idx)
{
    __shared__ SharedLDS S;
    const int bid = blockIdx.x;
    const int tid = threadIdx.x;
    const int lane = tid & 63;
    const int wid  = tid >> 6;

    if (bid < FPS_BLOCKS) {
        // =========================== FPS (batch = bid) ===============================
        const int b = bid;
        const float* base = xyz + (size_t)b * N_PTS * 6;
        const float4* b4 = (const float4*)base;

        float sx[K1_PPT], sy[K1_PPT], sz[K1_PPT], dd[K1_PPT];
        const int tb = tid * 24;
#pragma unroll
        for (int c = 0; c < 4; ++c) {
            float4 f0 = b4[tb + c * 6 + 0];
            float4 f1 = b4[tb + c * 6 + 1];
            float4 f2 = b4[tb + c * 6 + 2];
            float4 f3 = b4[tb + c * 6 + 3];
            float4 f4 = b4[tb + c * 6 + 4];
            float4 f5 = b4[tb + c * 6 + 5];
            sx[c*4+0] = f0.x; sy[c*4+0] = f0.y; sz[c*4+0] = f0.z;
            sx[c*4+1] = f1.z; sy[c*4+1] = f1.w; sz[c*4+1] = f2.x;
            sx[c*4+2] = f3.x; sy[c*4+2] = f3.y; sz[c*4+2] = f3.z;
            sx[c*4+3] = f4.z; sy[c*4+3] = f4.w; sz[c*4+3] = f5.x;
        }
        // swizzled staging: point p = tid*16+i at A(p) = (i<<9)+tid (conflict-free)
#pragma unroll
        for (int i = 0; i < K1_PPT; ++i) {
            int a = (i << 9) + tid;
            S.f.lx[a] = sx[i]; S.f.ly[a] = sy[i]; S.f.lz[a] = sz[i];
            dd[i] = BIGF;
        }
        __syncthreads();

        unsigned cur = 0;
        float cx = S.f.lx[0], cy = S.f.ly[0], cz = S.f.lz[0];   // point 0: A(0)=0

        for (int it = 0; it < NGROUP; ++it) {
            if (tid == 0) {
                // single relaxed store: fire-and-forget to L2; datum doubles as flag
                __hip_atomic_store(&fps_idx[b * NGROUP + it], (int)cur,
                                   __ATOMIC_RELAXED, __HIP_MEMORY_SCOPE_AGENT);
            }
            if (it == NGROUP - 1) break;

            // min-update + inline first-max tracking (ascending i == ascending idx)
            float bestd = -1.0f;
            unsigned besti = 0;
#pragma unroll
            for (int i = 0; i < K1_PPT; ++i) {
                float d = sq_dist(sx[i], sy[i], sz[i], cx, cy, cz);
                dd[i] = fminf(dd[i], d);
                bool gt = dd[i] > bestd;
                bestd = gt ? dd[i] : bestd;
                besti = gt ? (unsigned)i : besti;
            }
            unsigned bestp = (unsigned)tid * K1_PPT + besti;

            // wave argmax: f32 DPP max, then first tied lane (= smallest global index)
            float wm = __int_as_float(rdlane63_i(__float_as_int(wave_fmax(bestd))));
            unsigned long long bal = __ballot(bestd == wm);
            int L = (int)(__ffsll((long long)bal) - 1);
            unsigned widx = (unsigned)__builtin_amdgcn_readlane((int)bestp, L);

            if (lane == 0) {
                int wa = (int)(((widx & 15u) << 9) + (widx >> 4));
                unsigned* pp = S.f.part[it & 1][wid];
                pp[0] = 0xFFFFFFFFu - widx;
                pp[1] = __float_as_uint(wm);
                pp[2] = __float_as_uint(S.f.lx[wa]);
                pp[3] = __float_as_uint(S.f.ly[wa]);
                pp[4] = __float_as_uint(S.f.lz[wa]);
            }
            __syncthreads();

            // block reduce over 8 partials: lanes 0..7, max valid in lane 7
            const unsigned* pp = S.f.part[it & 1][lane & 7];
            unsigned kl = pp[0], kh = pp[1];
            float xx = __uint_as_float(pp[2]);
            float yy = __uint_as_float(pp[3]);
            float zz = __uint_as_float(pp[4]);
            unsigned long long v = ((unsigned long long)kh << 32) | kl;
            U64_DPP_STEP(0x111, 0xF, >);
            U64_DPP_STEP(0x112, 0xF, >);
            U64_DPP_STEP(0x114, 0xF, >);
            unsigned wkl = (unsigned)__builtin_amdgcn_readlane((int)(unsigned)v, 7);
            cur = 0xFFFFFFFFu - wkl;
            int W = (int)(cur >> 10);   // 1024 pts/wave -> winning wave id
            cx = __int_as_float(__builtin_amdgcn_readlane(__float_as_int(xx), W));
            cy = __int_as_float(__builtin_amdgcn_readlane(__float_as_int(yy), W));
            cz = __int_as_float(__builtin_amdgcn_readlane(__float_as_int(zz), W));
        }
        return;
    }

    // ============================= kNN worker blocks =================================
    const int OFF1 = N_B * NGROUP * GSIZE * 3;   // neigh_attr
    const int OFF2 = 2 * OFF1;                   // center
    const int OFF3 = OFF2 + N_B * NGROUP * 3;    // center_attribute

    for (int idx = bid - FPS_BLOCKS; idx < N_B * NGROUP; idx += KNN_BLOCKS) {
        const int g = idx >> 3;
        const int b = idx & 7;
        const float* base = xyz + (size_t)b * N_PTS * 6;

        if (tid == 0) {
            // relaxed atomic spin on the datum itself (L2 read, caches stay warm)
            int qv;
            while ((qv = __hip_atomic_load(&fps_idx[b * NGROUP + g], __ATOMIC_RELAXED,
                                           __HIP_MEMORY_SCOPE_AGENT)) < 0)
                __builtin_amdgcn_s_sleep(32);
            S.k.qshare = qv;
        }
        __syncthreads();   // orders qshare + all S.k reuse from previous group

        const int qq = __builtin_amdgcn_readfirstlane(S.k.qshare);
        const float cx = base[qq * 6 + 0];
        const float cy = base[qq * 6 + 1];
        const float cz = base[qq * 6 + 2];
        // ||c||^2: separate square, left-assoc add, NO FMA
        const float cn = __fadd_rn(__fadd_rn(__fmul_rn(cx, cx), __fmul_rn(cy, cy)),
                                   __fmul_rn(cz, cz));

        const float4* b4 = (const float4*)base;
        const int tb = tid * 24;

        unsigned long long keys[K2_PPT];

#pragma unroll
        for (int c = 0; c < 4; ++c) {
            float4 f0 = b4[tb + c * 6 + 0];
            float4 f1 = b4[tb + c * 6 + 1];
            float4 f2 = b4[tb + c * 6 + 2];
            float4 f3 = b4[tb + c * 6 + 3];
            float4 f4 = b4[tb + c * 6 + 4];
            float4 f5 = b4[tb + c * 6 + 5];
            float X[4] = {f0.x, f1.z, f3.x, f4.z};
            float Y[4] = {f0.y, f1.w, f3.y, f4.w};
            float Z[4] = {f0.z, f2.x, f3.z, f5.x};
#pragma unroll
            for (int j = 0; j < 4; ++j) {
                float x = X[j], y = Y[j], z = Z[j];
                float xn  = __fadd_rn(__fadd_rn(__fmul_rn(x, x), __fmul_rn(y, y)), __fmul_rn(z, z));
                float dot = __fmul_rn(cx, x);
                dot = __fmaf_rn(cy, y, dot);
                dot = __fmaf_rn(cz, z, dot);
                float d2  = __fadd_rn(__fsub_rn(cn, __fmul_rn(2.0f, dot)), xn);
                int p = tid * K2_PPT + c * 4 + j;
                keys[c * 4 + j] =
                    ((unsigned long long)fxform(__float_as_uint(d2)) << 32) | (unsigned)p;
            }
        }

        bitonic_sort<K2_PPT>(keys);

        // per-wave top-32 extraction (ascending into wtop[wid])
        {
            unsigned long long cand = keys[0];
            unsigned w = 0;
            for (int r = 0; r < GSIZE; ++r) {
                unsigned ch = (unsigned)(cand >> 32);
                unsigned whd = (unsigned)rdlane63_i((int)wave_umin32(ch));
                unsigned long long bal = __ballot(ch == whd);
                unsigned wl;
                if (__popcll(bal) == 1) {
                    int L = (int)(__ffsll((long long)bal) - 1);
                    wl = (unsigned)__builtin_amdgcn_readlane((int)(unsigned)cand, L);
                } else {
                    unsigned cl = (ch == whd) ? (unsigned)cand : 0xFFFFFFFFu;
                    wl = (unsigned)rdlane63_i((int)wave_umin32(cl));
                }
                unsigned long long wkey = ((unsigned long long)whd << 32) | wl;
                if (lane == 0) S.k.wtop[wid][r] = wkey;
                if (cand == wkey) {   // exactly one lane (keys unique)
                    ++w;
                    unsigned long long nc;
                    if (w < 4) {
                        nc = (w == 1) ? keys[1] : (w == 2) ? keys[2] : keys[3];
                    } else if (w < K2_PPT) {
                        nc = keys[4];
#pragma unroll
                        for (int j = 5; j < K2_PPT; ++j) nc = (w == (unsigned)j) ? keys[j] : nc;
                    } else {
                        nc = ~0ull;
                    }
                    cand = nc;
                }
            }
        }
        __syncthreads();

        // parallel rank-merge: 256 threads, one candidate each
        if (tid < K2_WAVES * GSIZE) {
            const int w8 = tid >> 5, i = tid & 31;
            unsigned long long e = S.k.wtop[w8][i];
            int rank = 0;
#pragma unroll
            for (int l = 0; l < K2_WAVES; ++l) {
                const unsigned long long* arr = S.k.wtop[l];
                int lo = 0;
                if (arr[15]     < e) lo = 16;
                if (arr[lo + 7] < e) lo += 8;
                if (arr[lo + 3] < e) lo += 4;
                if (arr[lo + 1] < e) lo += 2;
                if (arr[lo]     < e) lo += 1;
                rank += lo;
            }
            if (rank < GSIZE) S.k.nlist[rank] = (unsigned)e;
        }
        __syncthreads();

        // ---- outputs ----
        if (tid < GSIZE) {
            unsigned p = S.k.nlist[tid];
            float x  = base[p * 6 + 0];
            float y  = base[p * 6 + 1];
            float z  = base[p * 6 + 2];
            float a0 = base[p * 6 + 3];
            float a1 = base[p * 6 + 4];
            float a2 = base[p * 6 + 5];
            size_t o = ((size_t)(b * NGROUP + g) * GSIZE + tid) * 3;
            out[o + 0] = __fsub_rn(x, cx);
            out[o + 1] = __fsub_rn(y, cy);
            out[o + 2] = __fsub_rn(z, cz);
            out[OFF1 + o + 0] = a0;
            out[OFF1 + o + 1] = a1;
            out[OFF1 + o + 2] = a2;
        } else if (tid == GSIZE) {
            size_t o = (size_t)(b * NGROUP + g) * 3;
            out[OFF2 + o + 0] = cx;
            out[OFF2 + o + 1] = cy;
            out[OFF2 + o + 2] = cz;
            out[OFF3 + o + 0] = base[qq * 6 + 3];
            out[OFF3 + o + 1] = base[qq * 6 + 4];
            out[OFF3 + o + 2] = base[qq * 6 + 5];
        }
        // no trailing barrier: next iteration's top __syncthreads orders S.k reuse
    }
}

extern "C" void kernel_launch(void* const* d_in, const int* in_sizes, int n_in,
                              void* d_out, int out_size, void* d_ws, size_t ws_size,
                              hipStream_t stream) {
    const float* xyz = (const float*)d_in[0];
    float* out = (float*)d_out;
    int* fps_idx = (int*)d_ws;   // 16 KB; 0xAA poison < 0 = "not ready" sentinel

    fused_kernel<<<TOT_BLOCKS, THREADS, 0, stream>>>(xyz, out, fps_idx);
}